// Round 7
// baseline (1878.510 us; speedup 1.0000x reference)
//
#include <hip/hip_runtime.h>

#define B_SZ 4096
#define D_SZ 4096
#define L_SZ 64
#define TAU_INV 10.0f
#define THRESH 32
#define NT 32                 // tiles per dim (4096/128)
#define TRI (NT * (NT + 1) / 2)   // 528 triangle tiles per matrix

// fp8 pre-scale: elements ~N(0, 1/64); x16 puts typical |v| ~ 0.25 into e4m3 sweet spot.
// products carry 16*16 = 256; folded into exp argument below.
#define FP8_PRESCALE 16.0f
#define EXP_SCALE (TAU_INV / 256.0f)

typedef __attribute__((ext_vector_type(8))) short bf16x8;
typedef __attribute__((ext_vector_type(4))) float f32x4;
typedef __attribute__((ext_vector_type(8))) int i32x8;

union fragu { i32x8 v; int4 h[2]; };

__device__ __forceinline__ unsigned short f2bf(float f) {
    union { float f; unsigned u; } v; v.f = f;
    unsigned r = v.u + 0x7fffu + ((v.u >> 16) & 1u);
    return (unsigned short)(r >> 16);
}

// float -> OCP e4m3fn, round-to-nearest-even (normals), RN (subnormals). (software fallback)
__device__ __forceinline__ unsigned f2fp8(float f) {
    union { float f; unsigned u; } v; v.f = f;
    unsigned s = (v.u >> 24) & 0x80u;
    float a = fabsf(f);
    if (a >= 0.015625f) {                       // normal e4m3 range
        if (a >= 448.0f) return s | 0x7Eu;      // clamp to max finite
        unsigned u = v.u & 0x7FFFFFFFu;
        u += 0x0007FFFFu + ((u >> 20) & 1u);    // RNE to 3 mantissa bits
        int e = (int)(u >> 23) - 120;           // rebias 127 -> 7
        if (e >= 16) return s | 0x7Eu;
        return s | (unsigned)(e << 3) | ((u >> 20) & 7u);
    } else {                                    // subnormal: units of 2^-9
        int m = (int)(a * 512.0f + 0.5f);       // 0..8 (8 == 2^-6 encodes as normal min)
        return s | (unsigned)m;
    }
}

// pack 4 scaled floats into 4 fp8 bytes (one dword). HW path: v_cvt_pk_fp8_f32
// (gfx950 = OCP e4m3fn, 2 instrs); fallback: software RNE chain.
__device__ __forceinline__ unsigned pack4_fp8(float4 v, float s) {
#if __has_builtin(__builtin_amdgcn_cvt_pk_fp8_f32)
    int p = __builtin_amdgcn_cvt_pk_fp8_f32(v.x * s, v.y * s, 0, false);   // bytes 0,1
    p = __builtin_amdgcn_cvt_pk_fp8_f32(v.z * s, v.w * s, p, true);        // bytes 2,3
    return (unsigned)p;
#else
    return f2fp8(v.x * s) | (f2fp8(v.y * s) << 8) |
           (f2fp8(v.z * s) << 16) | (f2fp8(v.w * s) << 24);
#endif
}

__device__ __forceinline__ void gload_lds16(const void* g, void* l) {
    __builtin_amdgcn_global_load_lds(
        (const __attribute__((address_space(1))) void*)g,
        (__attribute__((address_space(3))) void*)l, 16, 0, 0);
}

// ---------------- init ----------------
__global__ void init_kernel(double* acc, int* n_neg) {
    int t = threadIdx.x;
    if (t < 35) acc[t] = 0.0;      // [0]=pos(fallback) [1,2]=negx/negy [3..34]=pos partials
    if (t == 0) *n_neg = 0;
}

// ---------------- label mask ----------------
__global__ void mask_kernel(const int* __restrict__ labels, int* __restrict__ neg_mask,
                            int* __restrict__ n_neg) {
    int row = blockIdx.x * blockDim.x + threadIdx.x;
    if (row >= B_SZ) return;
    const int4* lr = reinterpret_cast<const int4*>(labels + (size_t)row * L_SZ);
    int cnt = 0;
#pragma unroll
    for (int i = 0; i < L_SZ / 4; i++) {
        int4 v = lr[i];
        cnt += (v.x == 0) + (v.y == 0) + (v.z == 0) + (v.w == 0);
    }
    int neg = (cnt > THRESH) ? 1 : 0;
    neg_mask[row] = neg;
    if (neg) atomicAdd(n_neg, 1);
}

// ---------------- fused norms + positive term + normalized fp8 write ----------------
__global__ __launch_bounds__(256) void norm_prep_fp8_kernel(const float* __restrict__ X,
                                                            const float* __restrict__ Y,
                                                            unsigned char* __restrict__ Xq,
                                                            unsigned char* __restrict__ Yq,
                                                            double* __restrict__ acc) {
    int row = blockIdx.x;
    int t = threadIdx.x;
    int lane = t & 63;
    int w = t >> 6;
    const float4* xr = reinterpret_cast<const float4*>(X + (size_t)row * D_SZ);
    const float4* yr = reinterpret_cast<const float4*>(Y + (size_t)row * D_SZ);
    float4 xv[4], yv[4];
    float sx = 0.f, sy = 0.f, dxy = 0.f;
#pragma unroll
    for (int i = 0; i < 4; i++) {
        xv[i] = xr[t + 256 * i];
        yv[i] = yr[t + 256 * i];
        sx  += xv[i].x * xv[i].x + xv[i].y * xv[i].y + xv[i].z * xv[i].z + xv[i].w * xv[i].w;
        sy  += yv[i].x * yv[i].x + yv[i].y * yv[i].y + yv[i].z * yv[i].z + yv[i].w * yv[i].w;
        dxy += xv[i].x * yv[i].x + xv[i].y * yv[i].y + xv[i].z * yv[i].z + xv[i].w * yv[i].w;
    }
    // wave-level butterfly reduce (64 lanes, no barriers)
#pragma unroll
    for (int off = 32; off > 0; off >>= 1) {
        sx  += __shfl_xor(sx, off, 64);
        sy  += __shfl_xor(sy, off, 64);
        dxy += __shfl_xor(dxy, off, 64);
    }
    __shared__ float wred[4][3];
    if (lane == 0) { wred[w][0] = sx; wred[w][1] = sy; wred[w][2] = dxy; }
    __syncthreads();
    float tsx  = wred[0][0] + wred[1][0] + wred[2][0] + wred[3][0];
    float tsy  = wred[0][1] + wred[1][1] + wred[2][1] + wred[3][1];
    float tdxy = wred[0][2] + wred[1][2] + wred[2][2] + wred[3][2];
    float inx = 1.0f / sqrtf(tsx);
    float iny = 1.0f / sqrtf(tsy);
    if (t == 0) {
        float cosv = tdxy * inx * iny;
        atomicAdd(&acc[3 + (row & 31)], (double)expf((1.0f - cosv) * TAU_INV));
    }
    float ex = inx * FP8_PRESCALE;
    float ey = iny * FP8_PRESCALE;
    unsigned* xd = reinterpret_cast<unsigned*>(Xq + (size_t)row * D_SZ);
    unsigned* yd = reinterpret_cast<unsigned*>(Yq + (size_t)row * D_SZ);
#pragma unroll
    for (int i = 0; i < 4; i++) {
        xd[t + 256 * i] = pack4_fp8(xv[i], ex);
        yd[t + 256 * i] = pack4_fp8(yv[i], ey);
    }
}

// legacy split norm (small-ws fallback path)
__global__ __launch_bounds__(256) void norm_kernel(const float* __restrict__ X,
                                                   const float* __restrict__ Y,
                                                   float* __restrict__ inv_nx,
                                                   float* __restrict__ inv_ny,
                                                   double* __restrict__ pos_sum) {
    int row = blockIdx.x;
    int t = threadIdx.x;
    const float4* xr = reinterpret_cast<const float4*>(X + (size_t)row * D_SZ);
    const float4* yr = reinterpret_cast<const float4*>(Y + (size_t)row * D_SZ);
    float sx = 0.f, sy = 0.f, dxy = 0.f;
    for (int i = t; i < D_SZ / 4; i += 256) {
        float4 xvv = xr[i];
        float4 yvv = yr[i];
        sx  += xvv.x * xvv.x + xvv.y * xvv.y + xvv.z * xvv.z + xvv.w * xvv.w;
        sy  += yvv.x * yvv.x + yvv.y * yvv.y + yvv.z * yvv.z + yvv.w * yvv.w;
        dxy += xvv.x * yvv.x + xvv.y * yvv.y + xvv.z * yvv.z + xvv.w * yvv.w;
    }
    __shared__ float rs0[256], rs1[256], rs2[256];
    rs0[t] = sx; rs1[t] = sy; rs2[t] = dxy;
    __syncthreads();
    for (int off = 128; off > 0; off >>= 1) {
        if (t < off) { rs0[t] += rs0[t + off]; rs1[t] += rs1[t + off]; rs2[t] += rs2[t + off]; }
        __syncthreads();
    }
    if (t == 0) {
        float inx = 1.0f / sqrtf(rs0[0]);
        float iny = 1.0f / sqrtf(rs1[0]);
        inv_nx[row] = inx;
        inv_ny[row] = iny;
        float cosv = rs2[0] * inx * iny;
        atomicAdd(pos_sum, (double)expf((1.0f - cosv) * TAU_INV));
    }
}

// ---------------- fused sim, MX-fp8 K=128: A from global (L1/L2), B in dbuf LDS ----------------
// R7: LDS pipe was ~70% busy (42us reads + 21us stage writes vs 30us MFMA). A-fragments
// now load directly from global (natural layout; per-instr the 64 lanes cover full
// 128B lines of 16 rows; within-block 2x reuse served by L1; panels L2/L3-resident).
// B keeps the proven chunk-permuted swizzled LDS path (0 conflicts), double-buffered
// in the SAME 32 KiB (16KB/panel) -> one barrier per K-step. LDS ops/wave-kstep: 24 -> 12.
// VGPR: acc64 + bfr32 + a0/a1 32 + addr ~20 = ~150 < 168 cap at (256,3). Watch WRITE_SIZE
// for spill (R4 lesson).
__global__ __launch_bounds__(256, 3) void sim_fused_fp8_kernel(const unsigned char* __restrict__ Xq,
                                                               const unsigned char* __restrict__ Yq,
                                                               const int* __restrict__ neg_mask,
                                                               double* __restrict__ accum2) {
    // bijective chunked XCD swizzle: 1056 = 8 * 132
    int b = blockIdx.x;
    int wg = (b & 7) * 132 + (b >> 3);
    int mat = (wg >= TRI) ? 1 : 0;
    int u = wg - mat * TRI;
    int ti = 0;
    while (u >= NT - ti) { u -= NT - ti; ti++; }
    int tj = ti + u;
    const unsigned char* Zq = mat ? Yq : Xq;

    __shared__ __align__(16) unsigned char Bs[2][16384];   // 2 x 16 KiB (B panels only)

    int t = threadIdx.x;
    int lane = t & 63;
    int w = t >> 6;
    int wr = w >> 1, wc = w & 1;
    int gi0 = ti * 128, gj0 = tj * 128;

    f32x4 acc[4][4];
#pragma unroll
    for (int m = 0; m < 4; m++)
#pragma unroll
        for (int n = 0; n < 4; n++) acc[m][n] = (f32x4){0.f, 0.f, 0.f, 0.f};

    // B staging: 16 segments of 8 rows x 128 B; lane covers row (lane>>3), phys chunk (lane&7).
    // physical chunk pc of row r holds logical chunk perm_inv(pc ^ (r&7)),
    // perm_inv(p) = ((p&3)<<1) | (p>>2)  (inverse of perm(c) = (c>>1) | ((c&1)<<2)).
    int srow_l = lane >> 3;
    int psx = (lane & 7) ^ srow_l;
    int scol_sw = (((psx & 3) << 1) | (psx >> 2)) * 16;   // logical chunk to fetch, in bytes

    // B fragment read: row = lane&15, logical chunks {2qh, 2qh+1} (qh = lane>>4).
    // physical = perm(c) ^ (row&7):  b=0 -> (qh)^rsw,  b=1 -> (qh+4)^rsw.
    int lrow = lane & 15;
    int qh = lane >> 4;
    int rsw = lrow & 7;
    int off0 = (qh ^ rsw) * 16;
    int off1 = ((qh + 4) ^ rsw) * 16;                      // == off0 ^ 64

    // A direct-global row pointers (natural layout; lane reads 16B at k0+qh*16 and +64)
    const unsigned char* aptr0 = Zq + (size_t)(gi0 + wr * 64 + 0 * 16 + lrow) * D_SZ + qh * 16;
    const unsigned char* aptr1 = Zq + (size_t)(gi0 + wr * 64 + 1 * 16 + lrow) * D_SZ + qh * 16;
    const unsigned char* aptr2 = Zq + (size_t)(gi0 + wr * 64 + 2 * 16 + lrow) * D_SZ + qh * 16;
    const unsigned char* aptr3 = Zq + (size_t)(gi0 + wr * 64 + 3 * 16 + lrow) * D_SZ + qh * 16;

    // prologue: stage B K-tile 0 into buf 0 (4 gload_lds per wave)
#pragma unroll
    for (int c = 0; c < 4; c++) {
        int s = w * 4 + c;
        int r = s * 8 + srow_l;
        gload_lds16(&Zq[(size_t)(gj0 + r) * D_SZ + scol_sw], &Bs[0][s * 1024]);
    }
    __syncthreads();

    int cur = 0;
    for (int k0 = 0; k0 < D_SZ; k0 += 128) {
        int notlast = (k0 + 128 < D_SZ);
        // prefetch next B panel into other buffer (overlaps with compute below)
        if (notlast) {
#pragma unroll
            for (int c = 0; c < 4; c++) {
                int s = w * 4 + c;
                int r = s * 8 + srow_l;
                gload_lds16(&Zq[(size_t)(gj0 + r) * D_SZ + (k0 + 128) + scol_sw],
                            &Bs[cur ^ 1][s * 1024]);
            }
        }

        // A fragments straight from global (L1 serves the wc-pair duplication)
        int4 a0_0 = *reinterpret_cast<const int4*>(aptr0 + k0);
        int4 a1_0 = *reinterpret_cast<const int4*>(aptr0 + k0 + 64);
        int4 a0_1 = *reinterpret_cast<const int4*>(aptr1 + k0);
        int4 a1_1 = *reinterpret_cast<const int4*>(aptr1 + k0 + 64);
        int4 a0_2 = *reinterpret_cast<const int4*>(aptr2 + k0);
        int4 a1_2 = *reinterpret_cast<const int4*>(aptr2 + k0 + 64);
        int4 a0_3 = *reinterpret_cast<const int4*>(aptr3 + k0);
        int4 a1_3 = *reinterpret_cast<const int4*>(aptr3 + k0 + 64);

        // B fragments from swizzled LDS
        fragu bfr[4];
#pragma unroll
        for (int n = 0; n < 4; n++) {
            int base = (wc * 64 + n * 16 + lrow) * 128;
            bfr[n].h[0] = *reinterpret_cast<const int4*>(&Bs[cur][base + off0]);
            bfr[n].h[1] = *reinterpret_cast<const int4*>(&Bs[cur][base + off1]);
        }

        fragu af;
        af.h[0] = a0_0; af.h[1] = a1_0;
#pragma unroll
        for (int n = 0; n < 4; n++)
            acc[0][n] = __builtin_amdgcn_mfma_scale_f32_16x16x128_f8f6f4(
                af.v, bfr[n].v, acc[0][n], 0, 0, 0, 0x7F7F7F7F, 0, 0x7F7F7F7F);
        af.h[0] = a0_1; af.h[1] = a1_1;
#pragma unroll
        for (int n = 0; n < 4; n++)
            acc[1][n] = __builtin_amdgcn_mfma_scale_f32_16x16x128_f8f6f4(
                af.v, bfr[n].v, acc[1][n], 0, 0, 0, 0x7F7F7F7F, 0, 0x7F7F7F7F);
        af.h[0] = a0_2; af.h[1] = a1_2;
#pragma unroll
        for (int n = 0; n < 4; n++)
            acc[2][n] = __builtin_amdgcn_mfma_scale_f32_16x16x128_f8f6f4(
                af.v, bfr[n].v, acc[2][n], 0, 0, 0, 0x7F7F7F7F, 0, 0x7F7F7F7F);
        af.h[0] = a0_3; af.h[1] = a1_3;
#pragma unroll
        for (int n = 0; n < 4; n++)
            acc[3][n] = __builtin_amdgcn_mfma_scale_f32_16x16x128_f8f6f4(
                af.v, bfr[n].v, acc[3][n], 0, 0, 0, 0x7F7F7F7F, 0, 0x7F7F7F7F);

        if (notlast) {      // drains next-B stage; orders buf reuse
            __syncthreads();
            cur ^= 1;
        }
    }

    // epilogue: C/D mapping col = lane&15, row = (lane>>4)*4 + reg (shape-determined)
    int lr4 = (lane >> 4) * 4;
    int lc = lane & 15;
    int negr[4][4], negc[4];
#pragma unroll
    for (int n = 0; n < 4; n++) negc[n] = neg_mask[gj0 + wc * 64 + n * 16 + lc];
#pragma unroll
    for (int m = 0; m < 4; m++)
#pragma unroll
        for (int j = 0; j < 4; j++) negr[m][j] = neg_mask[gi0 + wr * 64 + m * 16 + lr4 + j];

    float s = 0.f;
#pragma unroll
    for (int m = 0; m < 4; m++) {
#pragma unroll
        for (int n = 0; n < 4; n++) {
            int gj = gj0 + wc * 64 + n * 16 + lc;
            f32x4 a = acc[m][n];
#pragma unroll
            for (int j = 0; j < 4; j++) {
                int gi = gi0 + wr * 64 + m * 16 + lr4 + j;
                if (gi < gj && (negr[m][j] != negc[n]))
                    s += expf(a[j] * EXP_SCALE);
            }
        }
    }

    float* red = reinterpret_cast<float*>(&Bs[0][0]);   // alias: LDS stays 32 KiB
    __syncthreads();                                    // all waves done reading Bs
    red[t] = s;
    __syncthreads();
    for (int off = 128; off > 0; off >>= 1) {
        if (t < off) red[t] += red[t + off];
        __syncthreads();
    }
    if (t == 0) atomicAdd(&accum2[mat], (double)red[0]);
}

// ---------------- small-ws fallback (f32 inputs) ----------------
#define BMF 128
#define BKF 32
#define LDKF 40
__global__ __launch_bounds__(256) void sim_mfma_kernel(const float* __restrict__ Z,
                                                       const float* __restrict__ inv_n,
                                                       const int* __restrict__ neg_mask,
                                                       double* __restrict__ accum) {
    int ti = blockIdx.y, tj = blockIdx.x;
    if (ti > tj) return;

    __shared__ unsigned short As[BMF][LDKF];
    __shared__ unsigned short Bs[BMF][LDKF];

    int t = threadIdx.x;
    int lane = t & 63;
    int w = t >> 6;
    int wr = w >> 1, wc = w & 1;
    int gi0 = ti * BMF, gj0 = tj * BMF;

    f32x4 acc[4][4];
#pragma unroll
    for (int m = 0; m < 4; m++)
#pragma unroll
        for (int n = 0; n < 4; n++) acc[m][n] = (f32x4){0.f, 0.f, 0.f, 0.f};

    int srow = t >> 3;
    int scol = (t & 7) * 4;

    float invA[4], invB[4];
#pragma unroll
    for (int i = 0; i < 4; i++) {
        invA[i] = inv_n[gi0 + srow + i * 32];
        invB[i] = inv_n[gj0 + srow + i * 32];
    }

    int lrow = lane & 15;
    int ko = (lane >> 4) * 8;

    for (int k0 = 0; k0 < D_SZ; k0 += BKF) {
        __syncthreads();
#pragma unroll
        for (int i = 0; i < 4; i++) {
            int r = srow + i * 32;
            float4 av = *reinterpret_cast<const float4*>(&Z[(size_t)(gi0 + r) * D_SZ + k0 + scol]);
            float4 bv = *reinterpret_cast<const float4*>(&Z[(size_t)(gj0 + r) * D_SZ + k0 + scol]);
            ushort4 ap, bp;
            ap.x = f2bf(av.x * invA[i]); ap.y = f2bf(av.y * invA[i]);
            ap.z = f2bf(av.z * invA[i]); ap.w = f2bf(av.w * invA[i]);
            bp.x = f2bf(bv.x * invB[i]); bp.y = f2bf(bv.y * invB[i]);
            bp.z = f2bf(bv.z * invB[i]); bp.w = f2bf(bv.w * invB[i]);
            *reinterpret_cast<ushort4*>(&As[r][scol]) = ap;
            *reinterpret_cast<ushort4*>(&Bs[r][scol]) = bp;
        }
        __syncthreads();

        bf16x8 afr[4], bfr[4];
#pragma unroll
        for (int m = 0; m < 4; m++)
            afr[m] = *reinterpret_cast<const bf16x8*>(&As[wr * 64 + m * 16 + lrow][ko]);
#pragma unroll
        for (int n = 0; n < 4; n++)
            bfr[n] = *reinterpret_cast<const bf16x8*>(&Bs[wc * 64 + n * 16 + lrow][ko]);
#pragma unroll
        for (int m = 0; m < 4; m++)
#pragma unroll
            for (int n = 0; n < 4; n++)
                acc[m][n] = __builtin_amdgcn_mfma_f32_16x16x32_bf16(afr[m], bfr[n], acc[m][n], 0, 0, 0);
    }

    int lr4 = (lane >> 4) * 4;
    int lc = lane & 15;
    int negr[4][4], negc[4];
#pragma unroll
    for (int n = 0; n < 4; n++) negc[n] = neg_mask[gj0 + wc * 64 + n * 16 + lc];
#pragma unroll
    for (int m = 0; m < 4; m++)
#pragma unroll
        for (int j = 0; j < 4; j++) negr[m][j] = neg_mask[gi0 + wr * 64 + m * 16 + lr4 + j];

    float s = 0.f;
#pragma unroll
    for (int m = 0; m < 4; m++) {
#pragma unroll
        for (int n = 0; n < 4; n++) {
            int gj = gj0 + wc * 64 + n * 16 + lc;
            f32x4 a = acc[m][n];
#pragma unroll
            for (int j = 0; j < 4; j++) {
                int gi = gi0 + wr * 64 + m * 16 + lr4 + j;
                if (gi < gj && (negr[m][j] != negc[n]))
                    s += expf(a[j] * TAU_INV);
            }
        }
    }

    __shared__ float red[256];
    red[t] = s;
    __syncthreads();
    for (int off = 128; off > 0; off >>= 1) {
        if (t < off) red[t] += red[t + off];
        __syncthreads();
    }
    if (t == 0) atomicAdd(accum, (double)red[0]);
}

// ---------------- final combine ----------------
__global__ void final_kernel(const double* __restrict__ acc, const int* __restrict__ n_neg,
                             float* __restrict__ out) {
    double pos = acc[0];
    for (int i = 3; i < 35; i++) pos += acc[i];
    pos /= (double)B_SZ;
    long long nn = *n_neg;
    long long cnt = nn * ((long long)B_SZ - nn);
    double neg = (cnt > 0) ? (acc[1] + acc[2]) / (double)cnt : 0.0;
    out[0] = (float)(pos + neg);
}

extern "C" void kernel_launch(void* const* d_in, const int* in_sizes, int n_in,
                              void* d_out, int out_size, void* d_ws, size_t ws_size,
                              hipStream_t stream) {
    const float* X = (const float*)d_in[0];
    const float* Y = (const float*)d_in[1];
    const int* labels = (const int*)d_in[2];
    float* out = (float*)d_out;

    char* ws = (char*)d_ws;
    double* acc = (double*)ws;                 // [0..2] main, [3..34] pos partials
    int* n_neg = (int*)(ws + 512);
    int* neg_mask = (int*)(ws + 1024);         // 16 KiB
    float* inv_nx = (float*)(ws + 20480);
    float* inv_ny = (float*)(ws + 36864);

    const size_t FP8_BYTES = (size_t)B_SZ * D_SZ;        // 16 MiB per matrix
    const size_t HDR = 65536;

    init_kernel<<<1, 64, 0, stream>>>(acc, n_neg);
    mask_kernel<<<B_SZ / 256, 256, 0, stream>>>(labels, neg_mask, n_neg);

    if (ws_size >= HDR + 2 * FP8_BYTES) {
        unsigned char* Xq = (unsigned char*)(ws + HDR);
        unsigned char* Yq = (unsigned char*)(ws + HDR + FP8_BYTES);
        norm_prep_fp8_kernel<<<B_SZ, 256, 0, stream>>>(X, Y, Xq, Yq, acc);
        sim_fused_fp8_kernel<<<2 * TRI, 256, 0, stream>>>(Xq, Yq, neg_mask, &acc[1]);
    } else {
        dim3 grid(NT, NT);
        norm_kernel<<<B_SZ, 256, 0, stream>>>(X, Y, inv_nx, inv_ny, &acc[0]);
        sim_mfma_kernel<<<grid, 256, 0, stream>>>(X, inv_nx, neg_mask, &acc[1]);
        sim_mfma_kernel<<<grid, 256, 0, stream>>>(Y, inv_ny, neg_mask, &acc[2]);
    }

    final_kernel<<<1, 1, 0, stream>>>(acc, n_neg, out);
}

// Round 8
// 1842.090 us; speedup vs baseline: 1.0198x; 1.0198x over previous
//
#include <hip/hip_runtime.h>

#define B_SZ 4096
#define D_SZ 4096
#define L_SZ 64
#define TAU_INV 10.0f
#define THRESH 32
#define NT 32                 // tiles per dim (4096/128)
#define TRI (NT * (NT + 1) / 2)   // 528 triangle tiles per matrix

// fp8 pre-scale: elements ~N(0, 1/64); x16 puts typical |v| ~ 0.25 into e4m3 sweet spot.
// products carry 16*16 = 256; folded into exp argument below.
#define FP8_PRESCALE 16.0f
#define EXP_SCALE (TAU_INV / 256.0f)

typedef __attribute__((ext_vector_type(8))) short bf16x8;
typedef __attribute__((ext_vector_type(4))) float f32x4;
typedef __attribute__((ext_vector_type(8))) int i32x8;

union fragu { i32x8 v; int4 h[2]; };

__device__ __forceinline__ unsigned short f2bf(float f) {
    union { float f; unsigned u; } v; v.f = f;
    unsigned r = v.u + 0x7fffu + ((v.u >> 16) & 1u);
    return (unsigned short)(r >> 16);
}

// float -> OCP e4m3fn, round-to-nearest-even (normals), RN (subnormals). (software fallback)
__device__ __forceinline__ unsigned f2fp8(float f) {
    union { float f; unsigned u; } v; v.f = f;
    unsigned s = (v.u >> 24) & 0x80u;
    float a = fabsf(f);
    if (a >= 0.015625f) {                       // normal e4m3 range
        if (a >= 448.0f) return s | 0x7Eu;      // clamp to max finite
        unsigned u = v.u & 0x7FFFFFFFu;
        u += 0x0007FFFFu + ((u >> 20) & 1u);    // RNE to 3 mantissa bits
        int e = (int)(u >> 23) - 120;           // rebias 127 -> 7
        if (e >= 16) return s | 0x7Eu;
        return s | (unsigned)(e << 3) | ((u >> 20) & 7u);
    } else {                                    // subnormal: units of 2^-9
        int m = (int)(a * 512.0f + 0.5f);       // 0..8 (8 == 2^-6 encodes as normal min)
        return s | (unsigned)m;
    }
}

// pack 4 scaled floats into 4 fp8 bytes (one dword). HW path: v_cvt_pk_fp8_f32
// (gfx950 = OCP e4m3fn, 2 instrs); fallback: software RNE chain.
__device__ __forceinline__ unsigned pack4_fp8(float4 v, float s) {
#if __has_builtin(__builtin_amdgcn_cvt_pk_fp8_f32)
    int p = __builtin_amdgcn_cvt_pk_fp8_f32(v.x * s, v.y * s, 0, false);   // bytes 0,1
    p = __builtin_amdgcn_cvt_pk_fp8_f32(v.z * s, v.w * s, p, true);        // bytes 2,3
    return (unsigned)p;
#else
    return f2fp8(v.x * s) | (f2fp8(v.y * s) << 8) |
           (f2fp8(v.z * s) << 16) | (f2fp8(v.w * s) << 24);
#endif
}

__device__ __forceinline__ void gload_lds16(const void* g, void* l) {
    __builtin_amdgcn_global_load_lds(
        (const __attribute__((address_space(1))) void*)g,
        (__attribute__((address_space(3))) void*)l, 16, 0, 0);
}

// ---------------- init ----------------
__global__ void init_kernel(double* acc, int* n_neg) {
    int t = threadIdx.x;
    if (t < 35) acc[t] = 0.0;      // [0]=pos(fallback) [1,2]=negx/negy [3..34]=pos partials
    if (t == 0) *n_neg = 0;
}

// ---------------- label mask ----------------
__global__ void mask_kernel(const int* __restrict__ labels, int* __restrict__ neg_mask,
                            int* __restrict__ n_neg) {
    int row = blockIdx.x * blockDim.x + threadIdx.x;
    if (row >= B_SZ) return;
    const int4* lr = reinterpret_cast<const int4*>(labels + (size_t)row * L_SZ);
    int cnt = 0;
#pragma unroll
    for (int i = 0; i < L_SZ / 4; i++) {
        int4 v = lr[i];
        cnt += (v.x == 0) + (v.y == 0) + (v.z == 0) + (v.w == 0);
    }
    int neg = (cnt > THRESH) ? 1 : 0;
    neg_mask[row] = neg;
    if (neg) atomicAdd(n_neg, 1);
}

// ---------------- fused norms + positive term + normalized fp8 write (PERMUTED layout) ----------------
// Global fp8 layout: within each 128-B k-block, logical 16B chunk c is stored at
// position p(c) = ((c&3)<<1)|(c>>2). Logical chunks {q, q+4} land contiguously at
// {2q, 2q+1} -> sim's A-operand is ONE aligned 32-B load (no operand assembly).
__global__ __launch_bounds__(256) void norm_prep_fp8_kernel(const float* __restrict__ X,
                                                            const float* __restrict__ Y,
                                                            unsigned char* __restrict__ Xq,
                                                            unsigned char* __restrict__ Yq,
                                                            double* __restrict__ acc) {
    int row = blockIdx.x;
    int t = threadIdx.x;
    int lane = t & 63;
    int w = t >> 6;
    const float4* xr = reinterpret_cast<const float4*>(X + (size_t)row * D_SZ);
    const float4* yr = reinterpret_cast<const float4*>(Y + (size_t)row * D_SZ);
    float4 xv[4], yv[4];
    float sx = 0.f, sy = 0.f, dxy = 0.f;
#pragma unroll
    for (int i = 0; i < 4; i++) {
        xv[i] = xr[t + 256 * i];
        yv[i] = yr[t + 256 * i];
        sx  += xv[i].x * xv[i].x + xv[i].y * xv[i].y + xv[i].z * xv[i].z + xv[i].w * xv[i].w;
        sy  += yv[i].x * yv[i].x + yv[i].y * yv[i].y + yv[i].z * yv[i].z + yv[i].w * yv[i].w;
        dxy += xv[i].x * yv[i].x + xv[i].y * yv[i].y + xv[i].z * yv[i].z + xv[i].w * yv[i].w;
    }
    // wave-level butterfly reduce (64 lanes, no barriers)
#pragma unroll
    for (int off = 32; off > 0; off >>= 1) {
        sx  += __shfl_xor(sx, off, 64);
        sy  += __shfl_xor(sy, off, 64);
        dxy += __shfl_xor(dxy, off, 64);
    }
    __shared__ float wred[4][3];
    if (lane == 0) { wred[w][0] = sx; wred[w][1] = sy; wred[w][2] = dxy; }
    __syncthreads();
    float tsx  = wred[0][0] + wred[1][0] + wred[2][0] + wred[3][0];
    float tsy  = wred[0][1] + wred[1][1] + wred[2][1] + wred[3][1];
    float tdxy = wred[0][2] + wred[1][2] + wred[2][2] + wred[3][2];
    float inx = 1.0f / sqrtf(tsx);
    float iny = 1.0f / sqrtf(tsy);
    if (t == 0) {
        float cosv = tdxy * inx * iny;
        atomicAdd(&acc[3 + (row & 31)], (double)expf((1.0f - cosv) * TAU_INV));
    }
    float ex = inx * FP8_PRESCALE;
    float ey = iny * FP8_PRESCALE;
    unsigned* xd = reinterpret_cast<unsigned*>(Xq + (size_t)row * D_SZ);
    unsigned* yd = reinterpret_cast<unsigned*>(Yq + (size_t)row * D_SZ);
#pragma unroll
    for (int i = 0; i < 4; i++) {
        int d = t + 256 * i;                 // logical dword index in row
        int c = (d >> 2) & 7;                // logical chunk within 128B k-block
        int pc = ((c & 3) << 1) | (c >> 2);  // physical chunk position
        int pidx = (d & ~31) | (pc << 2) | (d & 3);
        xd[pidx] = pack4_fp8(xv[i], ex);
        yd[pidx] = pack4_fp8(yv[i], ey);
    }
}

// legacy split norm (small-ws fallback path)
__global__ __launch_bounds__(256) void norm_kernel(const float* __restrict__ X,
                                                   const float* __restrict__ Y,
                                                   float* __restrict__ inv_nx,
                                                   float* __restrict__ inv_ny,
                                                   double* __restrict__ pos_sum) {
    int row = blockIdx.x;
    int t = threadIdx.x;
    const float4* xr = reinterpret_cast<const float4*>(X + (size_t)row * D_SZ);
    const float4* yr = reinterpret_cast<const float4*>(Y + (size_t)row * D_SZ);
    float sx = 0.f, sy = 0.f, dxy = 0.f;
    for (int i = t; i < D_SZ / 4; i += 256) {
        float4 xvv = xr[i];
        float4 yvv = yr[i];
        sx  += xvv.x * xvv.x + xvv.y * xvv.y + xvv.z * xvv.z + xvv.w * xvv.w;
        sy  += yvv.x * yvv.x + yvv.y * yvv.y + yvv.z * yvv.z + yvv.w * yvv.w;
        dxy += xvv.x * yvv.x + xvv.y * yvv.y + xvv.z * yvv.z + xvv.w * yvv.w;
    }
    __shared__ float rs0[256], rs1[256], rs2[256];
    rs0[t] = sx; rs1[t] = sy; rs2[t] = dxy;
    __syncthreads();
    for (int off = 128; off > 0; off >>= 1) {
        if (t < off) { rs0[t] += rs0[t + off]; rs1[t] += rs1[t + off]; rs2[t] += rs2[t + off]; }
        __syncthreads();
    }
    if (t == 0) {
        float inx = 1.0f / sqrtf(rs0[0]);
        float iny = 1.0f / sqrtf(rs1[0]);
        inv_nx[row] = inx;
        inv_ny[row] = iny;
        float cosv = rs2[0] * inx * iny;
        atomicAdd(pos_sum, (double)expf((1.0f - cosv) * TAU_INV));
    }
}

// ---------------- fused sim, MX-fp8 K=128: A = one 32B global load, B = dbuf swizzled LDS ----------------
// R8: A-operand is a SINGLE aligned i32x8 load from the permuted global layout
// (logical chunks {q,q+4} contiguous) -> no union assembly (the R4/R5/R7 scratch
// trigger). B path byte-identical to R2/R6 (0 conflicts), double-buffered in the
// same 32 KiB, ONE barrier per K-step. A loads issued BEFORE stage gloads so
// in-order vmcnt retirement lets MFMAs start at vmcnt(8) without draining prefetch.
__global__ __launch_bounds__(256, 3) void sim_fused_fp8_kernel(const unsigned char* __restrict__ Xq,
                                                               const unsigned char* __restrict__ Yq,
                                                               const int* __restrict__ neg_mask,
                                                               double* __restrict__ accum2) {
    // bijective chunked XCD swizzle: 1056 = 8 * 132
    int b = blockIdx.x;
    int wg = (b & 7) * 132 + (b >> 3);
    int mat = (wg >= TRI) ? 1 : 0;
    int u = wg - mat * TRI;
    int ti = 0;
    while (u >= NT - ti) { u -= NT - ti; ti++; }
    int tj = ti + u;
    const unsigned char* Zq = mat ? Yq : Xq;

    __shared__ __align__(16) unsigned char Bs[2][16384];   // 2 x 16 KiB (B panels only)

    int t = threadIdx.x;
    int lane = t & 63;
    int w = t >> 6;
    int wr = w >> 1, wc = w & 1;
    int gi0 = ti * 128, gj0 = tj * 128;

    f32x4 acc[4][4];
#pragma unroll
    for (int m = 0; m < 4; m++)
#pragma unroll
        for (int n = 0; n < 4; n++) acc[m][n] = (f32x4){0.f, 0.f, 0.f, 0.f};

    // B staging: 16 segments of 8 rows x 128 B; lane covers row (lane>>3), phys chunk (lane&7).
    // LDS physical chunk pc of row r must hold logical chunk perm_inv(pc^(r&7)) (R2 invariant);
    // in the permuted GLOBAL layout that logical chunk lives at global position
    // f(psx) = ((psx&1)<<2)|(psx>>1)  (composition p(perm_inv(psx)), verified by table).
    int srow_l = lane >> 3;
    int psx = (lane & 7) ^ srow_l;
    int scol_sw = (((psx & 1) << 2) | (psx >> 1)) * 16;

    // B fragment read: byte-identical to R2 (logical chunks {qh, qh+4}), 0 conflicts.
    int lrow = lane & 15;
    int qh = lane >> 4;
    int rsw = lrow & 7;
    int off0 = (qh ^ rsw) * 16;
    int off1 = ((qh + 4) ^ rsw) * 16;                      // == off0 ^ 64

    // A direct-global base: lane reads 32 contiguous bytes (= logical chunks {qh, qh+4}
    // in the permuted layout) at row (gi0 + wr*64 + m*16 + lrow), k-block k0.
    const unsigned char* abase = Zq + (size_t)(gi0 + wr * 64 + lrow) * D_SZ + qh * 32;

    // prologue: stage B K-tile 0 into buf 0 (4 gload_lds per wave)
#pragma unroll
    for (int c = 0; c < 4; c++) {
        int s = w * 4 + c;
        int r = s * 8 + srow_l;
        gload_lds16(&Zq[(size_t)(gj0 + r) * D_SZ + scol_sw], &Bs[0][s * 1024]);
    }
    __syncthreads();

    int cur = 0;
    for (int k0 = 0; k0 < D_SZ; k0 += 128) {
        int notlast = (k0 + 128 < D_SZ);

        // A loads FIRST (oldest in vmcnt queue -> usable at vmcnt(8) with stages in flight)
        i32x8 av0 = *reinterpret_cast<const i32x8*>(abase + k0);
        i32x8 av1 = *reinterpret_cast<const i32x8*>(abase + k0 + (size_t)16 * D_SZ);
        i32x8 av2 = *reinterpret_cast<const i32x8*>(abase + k0 + (size_t)32 * D_SZ);
        i32x8 av3 = *reinterpret_cast<const i32x8*>(abase + k0 + (size_t)48 * D_SZ);

        // prefetch next B panel into other buffer (stays outstanding across the MFMAs)
        if (notlast) {
#pragma unroll
            for (int c = 0; c < 4; c++) {
                int s = w * 4 + c;
                int r = s * 8 + srow_l;
                gload_lds16(&Zq[(size_t)(gj0 + r) * D_SZ + (k0 + 128) + scol_sw],
                            &Bs[cur ^ 1][s * 1024]);
            }
        }

        // B fragments from swizzled LDS (proven-clean union-from-LDS pattern)
        fragu bfr[4];
#pragma unroll
        for (int n = 0; n < 4; n++) {
            int base = (wc * 64 + n * 16 + lrow) * 128;
            bfr[n].h[0] = *reinterpret_cast<const int4*>(&Bs[cur][base + off0]);
            bfr[n].h[1] = *reinterpret_cast<const int4*>(&Bs[cur][base + off1]);
        }

#pragma unroll
        for (int n = 0; n < 4; n++)
            acc[0][n] = __builtin_amdgcn_mfma_scale_f32_16x16x128_f8f6f4(
                av0, bfr[n].v, acc[0][n], 0, 0, 0, 0x7F7F7F7F, 0, 0x7F7F7F7F);
#pragma unroll
        for (int n = 0; n < 4; n++)
            acc[1][n] = __builtin_amdgcn_mfma_scale_f32_16x16x128_f8f6f4(
                av1, bfr[n].v, acc[1][n], 0, 0, 0, 0x7F7F7F7F, 0, 0x7F7F7F7F);
#pragma unroll
        for (int n = 0; n < 4; n++)
            acc[2][n] = __builtin_amdgcn_mfma_scale_f32_16x16x128_f8f6f4(
                av2, bfr[n].v, acc[2][n], 0, 0, 0, 0x7F7F7F7F, 0, 0x7F7F7F7F);
#pragma unroll
        for (int n = 0; n < 4; n++)
            acc[3][n] = __builtin_amdgcn_mfma_scale_f32_16x16x128_f8f6f4(
                av3, bfr[n].v, acc[3][n], 0, 0, 0, 0x7F7F7F7F, 0, 0x7F7F7F7F);

        if (notlast) {      // drains next-B stage; orders buf reuse
            __syncthreads();
            cur ^= 1;
        }
    }

    // epilogue: C/D mapping col = lane&15, row = (lane>>4)*4 + reg (shape-determined)
    int lr4 = (lane >> 4) * 4;
    int lc = lane & 15;
    int negr[4][4], negc[4];
#pragma unroll
    for (int n = 0; n < 4; n++) negc[n] = neg_mask[gj0 + wc * 64 + n * 16 + lc];
#pragma unroll
    for (int m = 0; m < 4; m++)
#pragma unroll
        for (int j = 0; j < 4; j++) negr[m][j] = neg_mask[gi0 + wr * 64 + m * 16 + lr4 + j];

    float s = 0.f;
#pragma unroll
    for (int m = 0; m < 4; m++) {
#pragma unroll
        for (int n = 0; n < 4; n++) {
            int gj = gj0 + wc * 64 + n * 16 + lc;
            f32x4 a = acc[m][n];
#pragma unroll
            for (int j = 0; j < 4; j++) {
                int gi = gi0 + wr * 64 + m * 16 + lr4 + j;
                if (gi < gj && (negr[m][j] != negc[n]))
                    s += expf(a[j] * EXP_SCALE);
            }
        }
    }

    float* red = reinterpret_cast<float*>(&Bs[0][0]);   // alias: LDS stays 32 KiB
    __syncthreads();                                    // all waves done reading Bs
    red[t] = s;
    __syncthreads();
    for (int off = 128; off > 0; off >>= 1) {
        if (t < off) red[t] += red[t + off];
        __syncthreads();
    }
    if (t == 0) atomicAdd(&accum2[mat], (double)red[0]);
}

// ---------------- small-ws fallback (f32 inputs) ----------------
#define BMF 128
#define BKF 32
#define LDKF 40
__global__ __launch_bounds__(256) void sim_mfma_kernel(const float* __restrict__ Z,
                                                       const float* __restrict__ inv_n,
                                                       const int* __restrict__ neg_mask,
                                                       double* __restrict__ accum) {
    int ti = blockIdx.y, tj = blockIdx.x;
    if (ti > tj) return;

    __shared__ unsigned short As[BMF][LDKF];
    __shared__ unsigned short Bs[BMF][LDKF];

    int t = threadIdx.x;
    int lane = t & 63;
    int w = t >> 6;
    int wr = w >> 1, wc = w & 1;
    int gi0 = ti * BMF, gj0 = tj * BMF;

    f32x4 acc[4][4];
#pragma unroll
    for (int m = 0; m < 4; m++)
#pragma unroll
        for (int n = 0; n < 4; n++) acc[m][n] = (f32x4){0.f, 0.f, 0.f, 0.f};

    int srow = t >> 3;
    int scol = (t & 7) * 4;

    float invA[4], invB[4];
#pragma unroll
    for (int i = 0; i < 4; i++) {
        invA[i] = inv_n[gi0 + srow + i * 32];
        invB[i] = inv_n[gj0 + srow + i * 32];
    }

    int lrow = lane & 15;
    int ko = (lane >> 4) * 8;

    for (int k0 = 0; k0 < D_SZ; k0 += BKF) {
        __syncthreads();
#pragma unroll
        for (int i = 0; i < 4; i++) {
            int r = srow + i * 32;
            float4 av = *reinterpret_cast<const float4*>(&Z[(size_t)(gi0 + r) * D_SZ + k0 + scol]);
            float4 bv = *reinterpret_cast<const float4*>(&Z[(size_t)(gj0 + r) * D_SZ + k0 + scol]);
            ushort4 ap, bp;
            ap.x = f2bf(av.x * invA[i]); ap.y = f2bf(av.y * invA[i]);
            ap.z = f2bf(av.z * invA[i]); ap.w = f2bf(av.w * invA[i]);
            bp.x = f2bf(bv.x * invB[i]); bp.y = f2bf(bv.y * invB[i]);
            bp.z = f2bf(bv.z * invB[i]); bp.w = f2bf(bv.w * invB[i]);
            *reinterpret_cast<ushort4*>(&As[r][scol]) = ap;
            *reinterpret_cast<ushort4*>(&Bs[r][scol]) = bp;
        }
        __syncthreads();

        bf16x8 afr[4], bfr[4];
#pragma unroll
        for (int m = 0; m < 4; m++)
            afr[m] = *reinterpret_cast<const bf16x8*>(&As[wr * 64 + m * 16 + lrow][ko]);
#pragma unroll
        for (int n = 0; n < 4; n++)
            bfr[n] = *reinterpret_cast<const bf16x8*>(&Bs[wc * 64 + n * 16 + lrow][ko]);
#pragma unroll
        for (int m = 0; m < 4; m++)
#pragma unroll
            for (int n = 0; n < 4; n++)
                acc[m][n] = __builtin_amdgcn_mfma_f32_16x16x32_bf16(afr[m], bfr[n], acc[m][n], 0, 0, 0);
    }

    int lr4 = (lane >> 4) * 4;
    int lc = lane & 15;
    int negr[4][4], negc[4];
#pragma unroll
    for (int n = 0; n < 4; n++) negc[n] = neg_mask[gj0 + wc * 64 + n * 16 + lc];
#pragma unroll
    for (int m = 0; m < 4; m++)
#pragma unroll
        for (int j = 0; j < 4; j++) negr[m][j] = neg_mask[gi0 + wr * 64 + m * 16 + lr4 + j];

    float s = 0.f;
#pragma unroll
    for (int m = 0; m < 4; m++) {
#pragma unroll
        for (int n = 0; n < 4; n++) {
            int gj = gj0 + wc * 64 + n * 16 + lc;
            f32x4 a = acc[m][n];
#pragma unroll
            for (int j = 0; j < 4; j++) {
                int gi = gi0 + wr * 64 + m * 16 + lr4 + j;
                if (gi < gj && (negr[m][j] != negc[n]))
                    s += expf(a[j] * TAU_INV);
            }
        }
    }

    __shared__ float red[256];
    red[t] = s;
    __syncthreads();
    for (int off = 128; off > 0; off >>= 1) {
        if (t < off) red[t] += red[t + off];
        __syncthreads();
    }
    if (t == 0) atomicAdd(accum, (double)red[0]);
}

// ---------------- final combine ----------------
__global__ void final_kernel(const double* __restrict__ acc, const int* __restrict__ n_neg,
                             float* __restrict__ out) {
    double pos = acc[0];
    for (int i = 3; i < 35; i++) pos += acc[i];
    pos /= (double)B_SZ;
    long long nn = *n_neg;
    long long cnt = nn * ((long long)B_SZ - nn);
    double neg = (cnt > 0) ? (acc[1] + acc[2]) / (double)cnt : 0.0;
    out[0] = (float)(pos + neg);
}

extern "C" void kernel_launch(void* const* d_in, const int* in_sizes, int n_in,
                              void* d_out, int out_size, void* d_ws, size_t ws_size,
                              hipStream_t stream) {
    const float* X = (const float*)d_in[0];
    const float* Y = (const float*)d_in[1];
    const int* labels = (const int*)d_in[2];
    float* out = (float*)d_out;

    char* ws = (char*)d_ws;
    double* acc = (double*)ws;                 // [0..2] main, [3..34] pos partials
    int* n_neg = (int*)(ws + 512);
    int* neg_mask = (int*)(ws + 1024);         // 16 KiB
    float* inv_nx = (float*)(ws + 20480);
    float* inv_ny = (float*)(ws + 36864);

    const size_t FP8_BYTES = (size_t)B_SZ * D_SZ;        // 16 MiB per matrix
    const size_t HDR = 65536;

    init_kernel<<<1, 64, 0, stream>>>(acc, n_neg);
    mask_kernel<<<B_SZ / 256, 256, 0, stream>>>(labels, neg_mask, n_neg);

    if (ws_size >= HDR + 2 * FP8_BYTES) {
        unsigned char* Xq = (unsigned char*)(ws + HDR);
        unsigned char* Yq = (unsigned char*)(ws + HDR + FP8_BYTES);
        norm_prep_fp8_kernel<<<B_SZ, 256, 0, stream>>>(X, Y, Xq, Yq, acc);
        sim_fused_fp8_kernel<<<2 * TRI, 256, 0, stream>>>(Xq, Yq, neg_mask, &acc[1]);
    } else {
        dim3 grid(NT, NT);
        norm_kernel<<<B_SZ, 256, 0, stream>>>(X, Y, inv_nx, inv_ny, &acc[0]);
        sim_mfma_kernel<<<grid, 256, 0, stream>>>(X, inv_nx, neg_mask, &acc[1]);
        sim_mfma_kernel<<<grid, 256, 0, stream>>>(Y, inv_ny, neg_mask, &acc[2]);
    }

    final_kernel<<<1, 1, 0, stream>>>(acc, n_neg, out);
}

// Round 9
// 105.370 us; speedup vs baseline: 17.8278x; 17.4821x over previous
//
#include <hip/hip_runtime.h>

#define B_SZ 4096
#define D_SZ 4096
#define L_SZ 64
#define TAU_INV 10.0f
#define THRESH 32
#define NT 32                 // tiles per dim (4096/128)
#define TRI (NT * (NT + 1) / 2)   // 528 triangle tiles per matrix

#define DB4 2048              // bytes per row at fp4 (4096 elems * 0.5 B)

// fp4 pre-scale: normalized elements ~N(0, 1/4096), sigma=1/64. Prescale 160 puts
// sigma at 2.5 on the e2m1 grid {0,.5,1,1.5,2,3,4,6} -> quantization delta ~0.11 RMS.
// Products carry 160*160 = 25600; folded into exp argument. (Verified absmax 0.0 in R4/R5.)
#define FP4_PRESCALE 160.0f
#define EXP_SCALE4 (TAU_INV / 25600.0f)

typedef __attribute__((ext_vector_type(8))) short bf16x8;
typedef __attribute__((ext_vector_type(4))) float f32x4;
typedef __attribute__((ext_vector_type(8))) int i32x8;

union fragu { i32x8 v; int4 h[2]; };

__device__ __forceinline__ unsigned short f2bf(float f) {
    union { float f; unsigned u; } v; v.f = f;
    unsigned r = v.u + 0x7fffu + ((v.u >> 16) & 1u);
    return (unsigned short)(r >> 16);
}

// float -> e2m1 fp4 code (monotone threshold chain; verified absmax 0.0 in R4/R5).
__device__ __forceinline__ unsigned f2fp4(float f) {
    float a = fabsf(f);
    unsigned code = (unsigned)(a >= 0.25f) + (a >= 0.75f) + (a >= 1.25f) + (a >= 1.75f)
                  + (a >= 2.5f) + (a >= 3.5f) + (a >= 5.0f);
    return code | ((__float_as_uint(f) >> 28) & 8u);
}

__device__ __forceinline__ unsigned short enc4(float4 v, float s) {
    unsigned n0 = f2fp4(v.x * s), n1 = f2fp4(v.y * s),
             n2 = f2fp4(v.z * s), n3 = f2fp4(v.w * s);
    return (unsigned short)(n0 | (n1 << 4) | (n2 << 8) | (n3 << 12));
}

__device__ __forceinline__ void gload_lds16(const void* g, void* l) {
    __builtin_amdgcn_global_load_lds(
        (const __attribute__((address_space(1))) void*)g,
        (__attribute__((address_space(3))) void*)l, 16, 0, 0);
}

// ---------------- init ----------------
__global__ void init_kernel(double* acc, int* n_neg) {
    int t = threadIdx.x;
    if (t < 35) acc[t] = 0.0;      // [0]=pos(fallback) [1,2]=negx/negy [3..34]=pos partials
    if (t == 0) *n_neg = 0;
}

// ---------------- label mask ----------------
__global__ void mask_kernel(const int* __restrict__ labels, int* __restrict__ neg_mask,
                            int* __restrict__ n_neg) {
    int row = blockIdx.x * blockDim.x + threadIdx.x;
    if (row >= B_SZ) return;
    const int4* lr = reinterpret_cast<const int4*>(labels + (size_t)row * L_SZ);
    int cnt = 0;
#pragma unroll
    for (int i = 0; i < L_SZ / 4; i++) {
        int4 v = lr[i];
        cnt += (v.x == 0) + (v.y == 0) + (v.z == 0) + (v.w == 0);
    }
    int neg = (cnt > THRESH) ? 1 : 0;
    neg_mask[row] = neg;
    if (neg) atomicAdd(n_neg, 1);
}

// ---------------- fused norms + positive term + normalized fp4 write (linear layout) ----------------
__global__ __launch_bounds__(256) void norm_prep_fp4_kernel(const float* __restrict__ X,
                                                            const float* __restrict__ Y,
                                                            unsigned char* __restrict__ Xq,
                                                            unsigned char* __restrict__ Yq,
                                                            double* __restrict__ acc) {
    int row = blockIdx.x;
    int t = threadIdx.x;
    int lane = t & 63;
    int w = t >> 6;
    const float4* xr = reinterpret_cast<const float4*>(X + (size_t)row * D_SZ);
    const float4* yr = reinterpret_cast<const float4*>(Y + (size_t)row * D_SZ);
    float4 xv[4], yv[4];
    float sx = 0.f, sy = 0.f, dxy = 0.f;
#pragma unroll
    for (int i = 0; i < 4; i++) {
        xv[i] = xr[t + 256 * i];
        yv[i] = yr[t + 256 * i];
        sx  += xv[i].x * xv[i].x + xv[i].y * xv[i].y + xv[i].z * xv[i].z + xv[i].w * xv[i].w;
        sy  += yv[i].x * yv[i].x + yv[i].y * yv[i].y + yv[i].z * yv[i].z + yv[i].w * yv[i].w;
        dxy += xv[i].x * yv[i].x + xv[i].y * yv[i].y + xv[i].z * yv[i].z + xv[i].w * yv[i].w;
    }
    // wave-level butterfly reduce (64 lanes, no barriers)
#pragma unroll
    for (int off = 32; off > 0; off >>= 1) {
        sx  += __shfl_xor(sx, off, 64);
        sy  += __shfl_xor(sy, off, 64);
        dxy += __shfl_xor(dxy, off, 64);
    }
    __shared__ float wred[4][3];
    if (lane == 0) { wred[w][0] = sx; wred[w][1] = sy; wred[w][2] = dxy; }
    __syncthreads();
    float tsx  = wred[0][0] + wred[1][0] + wred[2][0] + wred[3][0];
    float tsy  = wred[0][1] + wred[1][1] + wred[2][1] + wred[3][1];
    float tdxy = wred[0][2] + wred[1][2] + wred[2][2] + wred[3][2];
    float inx = 1.0f / sqrtf(tsx);
    float iny = 1.0f / sqrtf(tsy);
    if (t == 0) {
        float cosv = tdxy * inx * iny;
        atomicAdd(&acc[3 + (row & 31)], (double)expf((1.0f - cosv) * TAU_INV));
    }
    float ex = inx * FP4_PRESCALE;
    float ey = iny * FP4_PRESCALE;
    // elems [1024i + 4t, +4) -> ushort index row*1024 + 256i + t (coalesced, linear)
    unsigned short* xd = reinterpret_cast<unsigned short*>(Xq) + (size_t)row * 1024;
    unsigned short* yd = reinterpret_cast<unsigned short*>(Yq) + (size_t)row * 1024;
#pragma unroll
    for (int i = 0; i < 4; i++) {
        xd[256 * i + t] = enc4(xv[i], ex);
        yd[256 * i + t] = enc4(yv[i], ey);
    }
}

// legacy split norm (small-ws fallback path)
__global__ __launch_bounds__(256) void norm_kernel(const float* __restrict__ X,
                                                   const float* __restrict__ Y,
                                                   float* __restrict__ inv_nx,
                                                   float* __restrict__ inv_ny,
                                                   double* __restrict__ pos_sum) {
    int row = blockIdx.x;
    int t = threadIdx.x;
    const float4* xr = reinterpret_cast<const float4*>(X + (size_t)row * D_SZ);
    const float4* yr = reinterpret_cast<const float4*>(Y + (size_t)row * D_SZ);
    float sx = 0.f, sy = 0.f, dxy = 0.f;
    for (int i = t; i < D_SZ / 4; i += 256) {
        float4 xvv = xr[i];
        float4 yvv = yr[i];
        sx  += xvv.x * xvv.x + xvv.y * xvv.y + xvv.z * xvv.z + xvv.w * xvv.w;
        sy  += yvv.x * yvv.x + yvv.y * yvv.y + yvv.z * yvv.z + yvv.w * yvv.w;
        dxy += xvv.x * yvv.x + xvv.y * yvv.y + xvv.z * yvv.z + xvv.w * yvv.w;
    }
    __shared__ float rs0[256], rs1[256], rs2[256];
    rs0[t] = sx; rs1[t] = sy; rs2[t] = dxy;
    __syncthreads();
    for (int off = 128; off > 0; off >>= 1) {
        if (t < off) { rs0[t] += rs0[t + off]; rs1[t] += rs1[t + off]; rs2[t] += rs2[t + off]; }
        __syncthreads();
    }
    if (t == 0) {
        float inx = 1.0f / sqrtf(rs0[0]);
        float iny = 1.0f / sqrtf(rs1[0]);
        inv_nx[row] = inx;
        inv_ny[row] = iny;
        float cosv = rs2[0] * inx * iny;
        atomicAdd(pos_sum, (double)expf((1.0f - cosv) * TAU_INV));
    }
}

// ---------------- fused sim, MX-fp4, K-step=256: R6 body with cbsz=blgp=4 ----------------
// R9: fp4 data, but the inner loop is INSTRUCTION-FOR-INSTRUCTION the proven-clean R6
// shape: every MFMA operand is a fragu whose BOTH halves come from ds_read_b128 (the
// only pattern that doesn't trigger the accumulator-scratch pathology; R4/R5/R7/R8
// all deviated and all spilled ~1-2 GB). fp4 consumes only regs[0:3] of the 8-tuple
// (h[0]); h[1] is a real-but-ignored LDS read. K-step = 256 elems = 128 B/row -> same
// 16 KB panels, 32 KiB LDS, same swizzle bytes; each K-step = 2 half-steps with
// (off_lo, off_hi) swapped. Staging bytes and barriers HALVE vs R6; MFMA rate ~1.55x.
__global__ __launch_bounds__(256, 3) void sim_fused_fp4_kernel(const unsigned char* __restrict__ Xq,
                                                               const unsigned char* __restrict__ Yq,
                                                               const int* __restrict__ neg_mask,
                                                               double* __restrict__ accum2) {
    // bijective chunked XCD swizzle: 1056 = 8 * 132
    int b = blockIdx.x;
    int wg = (b & 7) * 132 + (b >> 3);
    int mat = (wg >= TRI) ? 1 : 0;
    int u = wg - mat * TRI;
    int ti = 0;
    while (u >= NT - ti) { u -= NT - ti; ti++; }
    int tj = ti + u;
    const unsigned char* Zq = mat ? Yq : Xq;

    __shared__ __align__(16) unsigned char As[128 * 128];   // 16 KiB (128 rows x 128 B = K=256 fp4)
    __shared__ __align__(16) unsigned char Bs[128 * 128];   // 16 KiB

    int t = threadIdx.x;
    int lane = t & 63;
    int w = t >> 6;
    int wr = w >> 1, wc = w & 1;
    int gi0 = ti * 128, gj0 = tj * 128;

    f32x4 acc[4][4];
#pragma unroll
    for (int m = 0; m < 4; m++)
#pragma unroll
        for (int n = 0; n < 4; n++) acc[m][n] = (f32x4){0.f, 0.f, 0.f, 0.f};

    // staging: 16 segments of 8 rows x 128 B; lane covers row (lane>>3), phys chunk (lane&7).
    // physical chunk pc of row r holds logical chunk perm_inv(pc ^ (r&7)),
    // perm_inv(p) = ((p&3)<<1) | (p>>2)  (same byte-level swizzle as R2/R6; dtype-agnostic).
    int srow_l = lane >> 3;
    int psx = (lane & 7) ^ srow_l;
    int scol_sw = (((psx & 3) << 1) | (psx >> 2)) * 16;   // logical 16B chunk to fetch

    // fragment read: row = lane&15, logical chunks {qh, qh+4} at swizzled offsets.
    int lrow = lane & 15;
    int qh = lane >> 4;
    int rsw = lrow & 7;
    int off0 = (qh ^ rsw) * 16;          // logical chunk qh      -> fp4 k-elems [ 32qh,  32qh+32)
    int off1 = ((qh + 4) ^ rsw) * 16;    // logical chunk qh+4    -> fp4 k-elems [128+32qh, +32)

    for (int kb = 0; kb < DB4; kb += 128) {   // 16 K-steps of 256 elems (128 B/row)
        if (kb) __syncthreads();   // prior compute done before overwrite
#pragma unroll
        for (int c = 0; c < 4; c++) {
            int s = w * 4 + c;
            int r = s * 8 + srow_l;
            gload_lds16(&Zq[(size_t)(gi0 + r) * DB4 + kb + scol_sw], &As[s * 1024]);
            gload_lds16(&Zq[(size_t)(gj0 + r) * DB4 + kb + scol_sw], &Bs[s * 1024]);
        }
        __syncthreads();

        // two half-steps; body identical to R6's (both union halves from ds_read_b128)
#pragma unroll
        for (int hs = 0; hs < 2; hs++) {
            int lo = hs ? off1 : off0;     // h[0] = the half the fp4 MFMA consumes
            int hi = hs ? off0 : off1;     // h[1] = real read, ignored by FMT=fp4

            fragu bfr[4];
#pragma unroll
            for (int n = 0; n < 4; n++) {
                int base = (wc * 64 + n * 16 + lrow) * 128;
                bfr[n].h[0] = *reinterpret_cast<const int4*>(&Bs[base + lo]);
                bfr[n].h[1] = *reinterpret_cast<const int4*>(&Bs[base + hi]);
            }
            fragu afr[4];
#pragma unroll
            for (int m = 0; m < 4; m++) {
                int base = (wr * 64 + m * 16 + lrow) * 128;
                afr[m].h[0] = *reinterpret_cast<const int4*>(&As[base + lo]);
                afr[m].h[1] = *reinterpret_cast<const int4*>(&As[base + hi]);
            }
#pragma unroll
            for (int m = 0; m < 4; m++)
#pragma unroll
                for (int n = 0; n < 4; n++)
                    acc[m][n] = __builtin_amdgcn_mfma_scale_f32_16x16x128_f8f6f4(
                        afr[m].v, bfr[n].v, acc[m][n], 4, 4,   // cbsz=4, blgp=4: fp4
                        0, 0x7F7F7F7F, 0, 0x7F7F7F7F);         // scales = 1.0
        }
    }

    // epilogue: C/D mapping col = lane&15, row = (lane>>4)*4 + reg (shape-determined)
    int lr4 = (lane >> 4) * 4;
    int lc = lane & 15;
    int negr[4][4], negc[4];
#pragma unroll
    for (int n = 0; n < 4; n++) negc[n] = neg_mask[gj0 + wc * 64 + n * 16 + lc];
#pragma unroll
    for (int m = 0; m < 4; m++)
#pragma unroll
        for (int j = 0; j < 4; j++) negr[m][j] = neg_mask[gi0 + wr * 64 + m * 16 + lr4 + j];

    float s = 0.f;
#pragma unroll
    for (int m = 0; m < 4; m++) {
#pragma unroll
        for (int n = 0; n < 4; n++) {
            int gj = gj0 + wc * 64 + n * 16 + lc;
            f32x4 a = acc[m][n];
#pragma unroll
            for (int j = 0; j < 4; j++) {
                int gi = gi0 + wr * 64 + m * 16 + lr4 + j;
                if (gi < gj && (negr[m][j] != negc[n]))
                    s += expf(a[j] * EXP_SCALE4);
            }
        }
    }

    float* red = reinterpret_cast<float*>(As);   // alias: LDS stays 32 KiB
    __syncthreads();                             // all waves done reading As
    red[t] = s;
    __syncthreads();
    for (int off = 128; off > 0; off >>= 1) {
        if (t < off) red[t] += red[t + off];
        __syncthreads();
    }
    if (t == 0) atomicAdd(&accum2[mat], (double)red[0]);
}

// ---------------- small-ws fallback (f32 inputs) ----------------
#define BMF 128
#define BKF 32
#define LDKF 40
__global__ __launch_bounds__(256) void sim_mfma_kernel(const float* __restrict__ Z,
                                                       const float* __restrict__ inv_n,
                                                       const int* __restrict__ neg_mask,
                                                       double* __restrict__ accum) {
    int ti = blockIdx.y, tj = blockIdx.x;
    if (ti > tj) return;

    __shared__ unsigned short As[BMF][LDKF];
    __shared__ unsigned short Bs[BMF][LDKF];

    int t = threadIdx.x;
    int lane = t & 63;
    int w = t >> 6;
    int wr = w >> 1, wc = w & 1;
    int gi0 = ti * BMF, gj0 = tj * BMF;

    f32x4 acc[4][4];
#pragma unroll
    for (int m = 0; m < 4; m++)
#pragma unroll
        for (int n = 0; n < 4; n++) acc[m][n] = (f32x4){0.f, 0.f, 0.f, 0.f};

    int srow = t >> 3;
    int scol = (t & 7) * 4;

    float invA[4], invB[4];
#pragma unroll
    for (int i = 0; i < 4; i++) {
        invA[i] = inv_n[gi0 + srow + i * 32];
        invB[i] = inv_n[gj0 + srow + i * 32];
    }

    int lrow = lane & 15;
    int ko = (lane >> 4) * 8;

    for (int k0 = 0; k0 < D_SZ; k0 += BKF) {
        __syncthreads();
#pragma unroll
        for (int i = 0; i < 4; i++) {
            int r = srow + i * 32;
            float4 av = *reinterpret_cast<const float4*>(&Z[(size_t)(gi0 + r) * D_SZ + k0 + scol]);
            float4 bv = *reinterpret_cast<const float4*>(&Z[(size_t)(gj0 + r) * D_SZ + k0 + scol]);
            ushort4 ap, bp;
            ap.x = f2bf(av.x * invA[i]); ap.y = f2bf(av.y * invA[i]);
            ap.z = f2bf(av.z * invA[i]); ap.w = f2bf(av.w * invA[i]);
            bp.x = f2bf(bv.x * invB[i]); bp.y = f2bf(bv.y * invB[i]);
            bp.z = f2bf(bv.z * invB[i]); bp.w = f2bf(bv.w * invB[i]);
            *reinterpret_cast<ushort4*>(&As[r][scol]) = ap;
            *reinterpret_cast<ushort4*>(&Bs[r][scol]) = bp;
        }
        __syncthreads();

        bf16x8 afr[4], bfr[4];
#pragma unroll
        for (int m = 0; m < 4; m++)
            afr[m] = *reinterpret_cast<const bf16x8*>(&As[wr * 64 + m * 16 + lrow][ko]);
#pragma unroll
        for (int n = 0; n < 4; n++)
            bfr[n] = *reinterpret_cast<const bf16x8*>(&Bs[wc * 64 + n * 16 + lrow][ko]);
#pragma unroll
        for (int m = 0; m < 4; m++)
#pragma unroll
            for (int n = 0; n < 4; n++)
                acc[m][n] = __builtin_amdgcn_mfma_f32_16x16x32_bf16(afr[m], bfr[n], acc[m][n], 0, 0, 0);
    }

    int lr4 = (lane >> 4) * 4;
    int lc = lane & 15;
    int negr[4][4], negc[4];
#pragma unroll
    for (int n = 0; n < 4; n++) negc[n] = neg_mask[gj0 + wc * 64 + n * 16 + lc];
#pragma unroll
    for (int m = 0; m < 4; m++)
#pragma unroll
        for (int j = 0; j < 4; j++) negr[m][j] = neg_mask[gi0 + wr * 64 + m * 16 + lr4 + j];

    float s = 0.f;
#pragma unroll
    for (int m = 0; m < 4; m++) {
#pragma unroll
        for (int n = 0; n < 4; n++) {
            int gj = gj0 + wc * 64 + n * 16 + lc;
            f32x4 a = acc[m][n];
#pragma unroll
            for (int j = 0; j < 4; j++) {
                int gi = gi0 + wr * 64 + m * 16 + lr4 + j;
                if (gi < gj && (negr[m][j] != negc[n]))
                    s += expf(a[j] * TAU_INV);
            }
        }
    }

    __shared__ float red[256];
    red[t] = s;
    __syncthreads();
    for (int off = 128; off > 0; off >>= 1) {
        if (t < off) red[t] += red[t + off];
        __syncthreads();
    }
    if (t == 0) atomicAdd(accum, (double)red[0]);
}

// ---------------- final combine ----------------
__global__ void final_kernel(const double* __restrict__ acc, const int* __restrict__ n_neg,
                             float* __restrict__ out) {
    double pos = acc[0];
    for (int i = 3; i < 35; i++) pos += acc[i];
    pos /= (double)B_SZ;
    long long nn = *n_neg;
    long long cnt = nn * ((long long)B_SZ - nn);
    double neg = (cnt > 0) ? (acc[1] + acc[2]) / (double)cnt : 0.0;
    out[0] = (float)(pos + neg);
}

extern "C" void kernel_launch(void* const* d_in, const int* in_sizes, int n_in,
                              void* d_out, int out_size, void* d_ws, size_t ws_size,
                              hipStream_t stream) {
    const float* X = (const float*)d_in[0];
    const float* Y = (const float*)d_in[1];
    const int* labels = (const int*)d_in[2];
    float* out = (float*)d_out;

    char* ws = (char*)d_ws;
    double* acc = (double*)ws;                 // [0..2] main, [3..34] pos partials
    int* n_neg = (int*)(ws + 512);
    int* neg_mask = (int*)(ws + 1024);         // 16 KiB
    float* inv_nx = (float*)(ws + 20480);
    float* inv_ny = (float*)(ws + 36864);

    const size_t FP4_BYTES = (size_t)B_SZ * DB4;         // 8 MiB per matrix
    const size_t HDR = 65536;

    init_kernel<<<1, 64, 0, stream>>>(acc, n_neg);
    mask_kernel<<<B_SZ / 256, 256, 0, stream>>>(labels, neg_mask, n_neg);

    if (ws_size >= HDR + 2 * FP4_BYTES) {
        unsigned char* Xq = (unsigned char*)(ws + HDR);
        unsigned char* Yq = (unsigned char*)(ws + HDR + FP4_BYTES);
        norm_prep_fp4_kernel<<<B_SZ, 256, 0, stream>>>(X, Y, Xq, Yq, acc);
        sim_fused_fp4_kernel<<<2 * TRI, 256, 0, stream>>>(Xq, Yq, neg_mask, &acc[1]);
    } else {
        dim3 grid(NT, NT);
        norm_kernel<<<B_SZ, 256, 0, stream>>>(X, Y, inv_nx, inv_ny, &acc[0]);
        sim_mfma_kernel<<<grid, 256, 0, stream>>>(X, inv_nx, neg_mask, &acc[1]);
        sim_mfma_kernel<<<grid, 256, 0, stream>>>(Y, inv_ny, neg_mask, &acc[2]);
    }

    final_kernel<<<1, 1, 0, stream>>>(acc, n_neg, out);
}

// Round 10
// 105.369 us; speedup vs baseline: 17.8279x; 1.0000x over previous
//
#include <hip/hip_runtime.h>

#define B_SZ 4096
#define D_SZ 4096
#define L_SZ 64
#define TAU_INV 10.0f
#define THRESH 32
#define NT 32                 // tiles per dim (4096/128)
#define TRI (NT * (NT + 1) / 2)   // 528 triangle tiles per matrix

#define DB4 2048              // bytes per row at fp4 (4096 elems * 0.5 B)

// fp4 pre-scale: normalized elements ~N(0, 1/4096), sigma=1/64. Prescale 160 puts
// sigma at 2.5 on the e2m1 grid {0,.5,1,1.5,2,3,4,6} -> quantization delta ~0.11 RMS.
// Products carry 160*160 = 25600; folded into exp argument. (Verified absmax 0.0 R4/R5/R9.)
#define FP4_PRESCALE 160.0f
#define EXP_SCALE4 (TAU_INV / 25600.0f)

typedef __attribute__((ext_vector_type(8))) short bf16x8;
typedef __attribute__((ext_vector_type(4))) float f32x4;
typedef __attribute__((ext_vector_type(8))) int i32x8;

union fragu { i32x8 v; int4 h[2]; };

__device__ __forceinline__ unsigned short f2bf(float f) {
    union { float f; unsigned u; } v; v.f = f;
    unsigned r = v.u + 0x7fffu + ((v.u >> 16) & 1u);
    return (unsigned short)(r >> 16);
}

// float -> e2m1 fp4 code (monotone threshold chain; verified absmax 0.0 in R4/R5/R9).
__device__ __forceinline__ unsigned f2fp4(float f) {
    float a = fabsf(f);
    unsigned code = (unsigned)(a >= 0.25f) + (a >= 0.75f) + (a >= 1.25f) + (a >= 1.75f)
                  + (a >= 2.5f) + (a >= 3.5f) + (a >= 5.0f);
    return code | ((__float_as_uint(f) >> 28) & 8u);
}

// pack 8 consecutive elems (two float4) into one dword, nibble k = elem k (same
// byte layout as R9's enc4 pairs, just full-dword store granularity).
__device__ __forceinline__ unsigned enc8(float4 a, float4 b, float s) {
    return  f2fp4(a.x * s)        | (f2fp4(a.y * s) << 4)
         | (f2fp4(a.z * s) << 8)  | (f2fp4(a.w * s) << 12)
         | (f2fp4(b.x * s) << 16) | (f2fp4(b.y * s) << 20)
         | (f2fp4(b.z * s) << 24) | (f2fp4(b.w * s) << 28);
}

__device__ __forceinline__ void gload_lds16(const void* g, void* l) {
    __builtin_amdgcn_global_load_lds(
        (const __attribute__((address_space(1))) void*)g,
        (__attribute__((address_space(3))) void*)l, 16, 0, 0);
}

// ---------------- init ----------------
__global__ void init_kernel(double* acc, int* n_neg) {
    int t = threadIdx.x;
    if (t < 35) acc[t] = 0.0;      // [0]=pos(fallback) [1,2]=negx/negy [3..34]=pos partials
    if (t == 0) *n_neg = 0;
}

// ---------------- label mask ----------------
__global__ void mask_kernel(const int* __restrict__ labels, int* __restrict__ neg_mask,
                            int* __restrict__ n_neg) {
    int row = blockIdx.x * blockDim.x + threadIdx.x;
    if (row >= B_SZ) return;
    const int4* lr = reinterpret_cast<const int4*>(labels + (size_t)row * L_SZ);
    int cnt = 0;
#pragma unroll
    for (int i = 0; i < L_SZ / 4; i++) {
        int4 v = lr[i];
        cnt += (v.x == 0) + (v.y == 0) + (v.z == 0) + (v.w == 0);
    }
    int neg = (cnt > THRESH) ? 1 : 0;
    neg_mask[row] = neg;
    if (neg) atomicAdd(n_neg, 1);
}

// ---------------- fused norms + positive term + normalized fp4 write ----------------
// R10: thread handles 8 CONSECUTIVE elems per group (2 groups) -> fp4 stores are
// full dwords (1 KB/wave-instr), not ushorts. Same bytes, same nibble layout.
__global__ __launch_bounds__(256) void norm_prep_fp4_kernel(const float* __restrict__ X,
                                                            const float* __restrict__ Y,
                                                            unsigned char* __restrict__ Xq,
                                                            unsigned char* __restrict__ Yq,
                                                            double* __restrict__ acc) {
    int row = blockIdx.x;
    int t = threadIdx.x;
    int lane = t & 63;
    int w = t >> 6;
    const float4* xr = reinterpret_cast<const float4*>(X + (size_t)row * D_SZ);
    const float4* yr = reinterpret_cast<const float4*>(Y + (size_t)row * D_SZ);
    float4 xv[4], yv[4];   // [2j+q]: elems [2048j + 8t + 4q, +4)
    float sx = 0.f, sy = 0.f, dxy = 0.f;
#pragma unroll
    for (int j = 0; j < 2; j++) {
#pragma unroll
        for (int q = 0; q < 2; q++) {
            float4 xvv = xr[512 * j + 2 * t + q];
            float4 yvv = yr[512 * j + 2 * t + q];
            xv[2 * j + q] = xvv;
            yv[2 * j + q] = yvv;
            sx  += xvv.x * xvv.x + xvv.y * xvv.y + xvv.z * xvv.z + xvv.w * xvv.w;
            sy  += yvv.x * yvv.x + yvv.y * yvv.y + yvv.z * yvv.z + yvv.w * yvv.w;
            dxy += xvv.x * yvv.x + xvv.y * yvv.y + xvv.z * yvv.z + xvv.w * yvv.w;
        }
    }
    // wave-level butterfly reduce (64 lanes, no barriers)
#pragma unroll
    for (int off = 32; off > 0; off >>= 1) {
        sx  += __shfl_xor(sx, off, 64);
        sy  += __shfl_xor(sy, off, 64);
        dxy += __shfl_xor(dxy, off, 64);
    }
    __shared__ float wred[4][3];
    if (lane == 0) { wred[w][0] = sx; wred[w][1] = sy; wred[w][2] = dxy; }
    __syncthreads();
    float tsx  = wred[0][0] + wred[1][0] + wred[2][0] + wred[3][0];
    float tsy  = wred[0][1] + wred[1][1] + wred[2][1] + wred[3][1];
    float tdxy = wred[0][2] + wred[1][2] + wred[2][2] + wred[3][2];
    float inx = 1.0f / sqrtf(tsx);
    float iny = 1.0f / sqrtf(tsy);
    if (t == 0) {
        float cosv = tdxy * inx * iny;
        atomicAdd(&acc[3 + (row & 31)], (double)expf((1.0f - cosv) * TAU_INV));
    }
    float ex = inx * FP4_PRESCALE;
    float ey = iny * FP4_PRESCALE;
    unsigned* xd = reinterpret_cast<unsigned*>(Xq + (size_t)row * DB4);
    unsigned* yd = reinterpret_cast<unsigned*>(Yq + (size_t)row * DB4);
#pragma unroll
    for (int j = 0; j < 2; j++) {
        xd[256 * j + t] = enc8(xv[2 * j], xv[2 * j + 1], ex);
        yd[256 * j + t] = enc8(yv[2 * j], yv[2 * j + 1], ey);
    }
}

// legacy split norm (small-ws fallback path)
__global__ __launch_bounds__(256) void norm_kernel(const float* __restrict__ X,
                                                   const float* __restrict__ Y,
                                                   float* __restrict__ inv_nx,
                                                   float* __restrict__ inv_ny,
                                                   double* __restrict__ pos_sum) {
    int row = blockIdx.x;
    int t = threadIdx.x;
    const float4* xr = reinterpret_cast<const float4*>(X + (size_t)row * D_SZ);
    const float4* yr = reinterpret_cast<const float4*>(Y + (size_t)row * D_SZ);
    float sx = 0.f, sy = 0.f, dxy = 0.f;
    for (int i = t; i < D_SZ / 4; i += 256) {
        float4 xvv = xr[i];
        float4 yvv = yr[i];
        sx  += xvv.x * xvv.x + xvv.y * xvv.y + xvv.z * xvv.z + xvv.w * xvv.w;
        sy  += yvv.x * yvv.x + yvv.y * yvv.y + yvv.z * yvv.z + yvv.w * yvv.w;
        dxy += xvv.x * yvv.x + xvv.y * yvv.y + xvv.z * yvv.z + xvv.w * yvv.w;
    }
    __shared__ float rs0[256], rs1[256], rs2[256];
    rs0[t] = sx; rs1[t] = sy; rs2[t] = dxy;
    __syncthreads();
    for (int off = 128; off > 0; off >>= 1) {
        if (t < off) { rs0[t] += rs0[t + off]; rs1[t] += rs1[t + off]; rs2[t] += rs2[t + off]; }
        __syncthreads();
    }
    if (t == 0) {
        float inx = 1.0f / sqrtf(rs0[0]);
        float iny = 1.0f / sqrtf(rs1[0]);
        inv_nx[row] = inx;
        inv_ny[row] = iny;
        float cosv = rs2[0] * inx * iny;
        atomicAdd(pos_sum, (double)expf((1.0f - cosv) * TAU_INV));
    }
}

// ---------------- fused sim, MX-fp4, K-step=256, dedup'd LDS reads ----------------
// R10 vs R9: fp4 consumes only h[0] of the 8-reg operand; R9 filled h[1] with a real
// (wasted) ds_read_b128. Now ONE ds_read_b128 per fragment, value duplicated into
// both halves -> operand is still 100% ds_read-sourced (the proven-clean invariant;
// R4/R5's dirty variant was constant-zero h[1], NOT a dup). LDS reads halve:
// 512 -> 256 B/lane per K-step. Canary: WRITE_SIZE must stay ~33 KB.
__global__ __launch_bounds__(256, 3) void sim_fused_fp4_kernel(const unsigned char* __restrict__ Xq,
                                                               const unsigned char* __restrict__ Yq,
                                                               const int* __restrict__ neg_mask,
                                                               double* __restrict__ accum2) {
    // bijective chunked XCD swizzle: 1056 = 8 * 132
    int b = blockIdx.x;
    int wg = (b & 7) * 132 + (b >> 3);
    int mat = (wg >= TRI) ? 1 : 0;
    int u = wg - mat * TRI;
    int ti = 0;
    while (u >= NT - ti) { u -= NT - ti; ti++; }
    int tj = ti + u;
    const unsigned char* Zq = mat ? Yq : Xq;

    __shared__ __align__(16) unsigned char As[128 * 128];   // 16 KiB (128 rows x 128 B = K=256 fp4)
    __shared__ __align__(16) unsigned char Bs[128 * 128];   // 16 KiB

    int t = threadIdx.x;
    int lane = t & 63;
    int w = t >> 6;
    int wr = w >> 1, wc = w & 1;
    int gi0 = ti * 128, gj0 = tj * 128;

    f32x4 acc[4][4];
#pragma unroll
    for (int m = 0; m < 4; m++)
#pragma unroll
        for (int n = 0; n < 4; n++) acc[m][n] = (f32x4){0.f, 0.f, 0.f, 0.f};

    // staging: 16 segments of 8 rows x 128 B; lane covers row (lane>>3), phys chunk (lane&7).
    // physical chunk pc of row r holds logical chunk perm_inv(pc ^ (r&7)),
    // perm_inv(p) = ((p&3)<<1) | (p>>2)  (same byte-level swizzle as R2/R6/R9).
    int srow_l = lane >> 3;
    int psx = (lane & 7) ^ srow_l;
    int scol_sw = (((psx & 3) << 1) | (psx >> 2)) * 16;   // logical 16B chunk to fetch

    // fragment read: row = lane&15, logical chunk {qh} (hs=0) / {qh+4} (hs=1), swizzled.
    int lrow = lane & 15;
    int qh = lane >> 4;
    int rsw = lrow & 7;
    int off0 = (qh ^ rsw) * 16;          // logical chunk qh    -> fp4 k-elems [ 32qh, +32)
    int off1 = ((qh + 4) ^ rsw) * 16;    // logical chunk qh+4  -> fp4 k-elems [128+32qh, +32)

    for (int kb = 0; kb < DB4; kb += 128) {   // 16 K-steps of 256 elems (128 B/row)
        if (kb) __syncthreads();   // prior compute done before overwrite
#pragma unroll
        for (int c = 0; c < 4; c++) {
            int s = w * 4 + c;
            int r = s * 8 + srow_l;
            gload_lds16(&Zq[(size_t)(gi0 + r) * DB4 + kb + scol_sw], &As[s * 1024]);
            gload_lds16(&Zq[(size_t)(gj0 + r) * DB4 + kb + scol_sw], &Bs[s * 1024]);
        }
        __syncthreads();

        // two half-steps; ONE ds_read_b128 per fragment, duplicated into both halves
#pragma unroll
        for (int hs = 0; hs < 2; hs++) {
            int off = hs ? off1 : off0;

            fragu bfr[4];
#pragma unroll
            for (int n = 0; n < 4; n++) {
                int4 xb = *reinterpret_cast<const int4*>(&Bs[(wc * 64 + n * 16 + lrow) * 128 + off]);
                bfr[n].h[0] = xb;
                bfr[n].h[1] = xb;     // ignored by FMT=fp4; dup keeps operand ds_read-pure
            }
            fragu afr[4];
#pragma unroll
            for (int m = 0; m < 4; m++) {
                int4 xa = *reinterpret_cast<const int4*>(&As[(wr * 64 + m * 16 + lrow) * 128 + off]);
                afr[m].h[0] = xa;
                afr[m].h[1] = xa;
            }
#pragma unroll
            for (int m = 0; m < 4; m++)
#pragma unroll
                for (int n = 0; n < 4; n++)
                    acc[m][n] = __builtin_amdgcn_mfma_scale_f32_16x16x128_f8f6f4(
                        afr[m].v, bfr[n].v, acc[m][n], 4, 4,   // cbsz=4, blgp=4: fp4
                        0, 0x7F7F7F7F, 0, 0x7F7F7F7F);         // scales = 1.0
        }
    }

    // epilogue: C/D mapping col = lane&15, row = (lane>>4)*4 + reg (shape-determined)
    int lr4 = (lane >> 4) * 4;
    int lc = lane & 15;
    int negr[4][4], negc[4];
#pragma unroll
    for (int n = 0; n < 4; n++) negc[n] = neg_mask[gj0 + wc * 64 + n * 16 + lc];
#pragma unroll
    for (int m = 0; m < 4; m++)
#pragma unroll
        for (int j = 0; j < 4; j++) negr[m][j] = neg_mask[gi0 + wr * 64 + m * 16 + lr4 + j];

    float s = 0.f;
#pragma unroll
    for (int m = 0; m < 4; m++) {
#pragma unroll
        for (int n = 0; n < 4; n++) {
            int gj = gj0 + wc * 64 + n * 16 + lc;
            f32x4 a = acc[m][n];
#pragma unroll
            for (int j = 0; j < 4; j++) {
                int gi = gi0 + wr * 64 + m * 16 + lr4 + j;
                if (gi < gj && (negr[m][j] != negc[n]))
                    s += expf(a[j] * EXP_SCALE4);
            }
        }
    }

    float* red = reinterpret_cast<float*>(As);   // alias: LDS stays 32 KiB
    __syncthreads();                             // all waves done reading As
    red[t] = s;
    __syncthreads();
    for (int off = 128; off > 0; off >>= 1) {
        if (t < off) red[t] += red[t + off];
        __syncthreads();
    }
    if (t == 0) atomicAdd(&accum2[mat], (double)red[0]);
}

// ---------------- small-ws fallback (f32 inputs) ----------------
#define BMF 128
#define BKF 32
#define LDKF 40
__global__ __launch_bounds__(256) void sim_mfma_kernel(const float* __restrict__ Z,
                                                       const float* __restrict__ inv_n,
                                                       const int* __restrict__ neg_mask,
                                                       double* __restrict__ accum) {
    int ti = blockIdx.y, tj = blockIdx.x;
    if (ti > tj) return;

    __shared__ unsigned short As[BMF][LDKF];
    __shared__ unsigned short Bs[BMF][LDKF];

    int t = threadIdx.x;
    int lane = t & 63;
    int w = t >> 6;
    int wr = w >> 1, wc = w & 1;
    int gi0 = ti * BMF, gj0 = tj * BMF;

    f32x4 acc[4][4];
#pragma unroll
    for (int m = 0; m < 4; m++)
#pragma unroll
        for (int n = 0; n < 4; n++) acc[m][n] = (f32x4){0.f, 0.f, 0.f, 0.f};

    int srow = t >> 3;
    int scol = (t & 7) * 4;

    float invA[4], invB[4];
#pragma unroll
    for (int i = 0; i < 4; i++) {
        invA[i] = inv_n[gi0 + srow + i * 32];
        invB[i] = inv_n[gj0 + srow + i * 32];
    }

    int lrow = lane & 15;
    int ko = (lane >> 4) * 8;

    for (int k0 = 0; k0 < D_SZ; k0 += BKF) {
        __syncthreads();
#pragma unroll
        for (int i = 0; i < 4; i++) {
            int r = srow + i * 32;
            float4 av = *reinterpret_cast<const float4*>(&Z[(size_t)(gi0 + r) * D_SZ + k0 + scol]);
            float4 bv = *reinterpret_cast<const float4*>(&Z[(size_t)(gj0 + r) * D_SZ + k0 + scol]);
            ushort4 ap, bp;
            ap.x = f2bf(av.x * invA[i]); ap.y = f2bf(av.y * invA[i]);
            ap.z = f2bf(av.z * invA[i]); ap.w = f2bf(av.w * invA[i]);
            bp.x = f2bf(bv.x * invB[i]); bp.y = f2bf(bv.y * invB[i]);
            bp.z = f2bf(bv.z * invB[i]); bp.w = f2bf(bv.w * invB[i]);
            *reinterpret_cast<ushort4*>(&As[r][scol]) = ap;
            *reinterpret_cast<ushort4*>(&Bs[r][scol]) = bp;
        }
        __syncthreads();

        bf16x8 afr[4], bfr[4];
#pragma unroll
        for (int m = 0; m < 4; m++)
            afr[m] = *reinterpret_cast<const bf16x8*>(&As[wr * 64 + m * 16 + lrow][ko]);
#pragma unroll
        for (int n = 0; n < 4; n++)
            bfr[n] = *reinterpret_cast<const bf16x8*>(&Bs[wc * 64 + n * 16 + lrow][ko]);
#pragma unroll
        for (int m = 0; m < 4; m++)
#pragma unroll
            for (int n = 0; n < 4; n++)
                acc[m][n] = __builtin_amdgcn_mfma_f32_16x16x32_bf16(afr[m], bfr[n], acc[m][n], 0, 0, 0);
    }

    int lr4 = (lane >> 4) * 4;
    int lc = lane & 15;
    int negr[4][4], negc[4];
#pragma unroll
    for (int n = 0; n < 4; n++) negc[n] = neg_mask[gj0 + wc * 64 + n * 16 + lc];
#pragma unroll
    for (int m = 0; m < 4; m++)
#pragma unroll
        for (int j = 0; j < 4; j++) negr[m][j] = neg_mask[gi0 + wr * 64 + m * 16 + lr4 + j];

    float s = 0.f;
#pragma unroll
    for (int m = 0; m < 4; m++) {
#pragma unroll
        for (int n = 0; n < 4; n++) {
            int gj = gj0 + wc * 64 + n * 16 + lc;
            f32x4 a = acc[m][n];
#pragma unroll
            for (int j = 0; j < 4; j++) {
                int gi = gi0 + wr * 64 + m * 16 + lr4 + j;
                if (gi < gj && (negr[m][j] != negc[n]))
                    s += expf(a[j] * TAU_INV);
            }
        }
    }

    __shared__ float red[256];
    red[t] = s;
    __syncthreads();
    for (int off = 128; off > 0; off >>= 1) {
        if (t < off) red[t] += red[t + off];
        __syncthreads();
    }
    if (t == 0) atomicAdd(accum, (double)red[0]);
}

// ---------------- final combine ----------------
__global__ void final_kernel(const double* __restrict__ acc, const int* __restrict__ n_neg,
                             float* __restrict__ out) {
    double pos = acc[0];
    for (int i = 3; i < 35; i++) pos += acc[i];
    pos /= (double)B_SZ;
    long long nn = *n_neg;
    long long cnt = nn * ((long long)B_SZ - nn);
    double neg = (cnt > 0) ? (acc[1] + acc[2]) / (double)cnt : 0.0;
    out[0] = (float)(pos + neg);
}

extern "C" void kernel_launch(void* const* d_in, const int* in_sizes, int n_in,
                              void* d_out, int out_size, void* d_ws, size_t ws_size,
                              hipStream_t stream) {
    const float* X = (const float*)d_in[0];
    const float* Y = (const float*)d_in[1];
    const int* labels = (const int*)d_in[2];
    float* out = (float*)d_out;

    char* ws = (char*)d_ws;
    double* acc = (double*)ws;                 // [0..2] main, [3..34] pos partials
    int* n_neg = (int*)(ws + 512);
    int* neg_mask = (int*)(ws + 1024);         // 16 KiB
    float* inv_nx = (float*)(ws + 20480);
    float* inv_ny = (float*)(ws + 36864);

    const size_t FP4_BYTES = (size_t)B_SZ * DB4;         // 8 MiB per matrix
    const size_t HDR = 65536;

    init_kernel<<<1, 64, 0, stream>>>(acc, n_neg);
    mask_kernel<<<B_SZ / 256, 256, 0, stream>>>(labels, neg_mask, n_neg);

    if (ws_size >= HDR + 2 * FP4_BYTES) {
        unsigned char* Xq = (unsigned char*)(ws + HDR);
        unsigned char* Yq = (unsigned char*)(ws + HDR + FP4_BYTES);
        norm_prep_fp4_kernel<<<B_SZ, 256, 0, stream>>>(X, Y, Xq, Yq, acc);
        sim_fused_fp4_kernel<<<2 * TRI, 256, 0, stream>>>(Xq, Yq, neg_mask, &acc[1]);
    } else {
        dim3 grid(NT, NT);
        norm_kernel<<<B_SZ, 256, 0, stream>>>(X, Y, inv_nx, inv_ny, &acc[0]);
        sim_mfma_kernel<<<grid, 256, 0, stream>>>(X, inv_nx, neg_mask, &acc[1]);
        sim_mfma_kernel<<<grid, 256, 0, stream>>>(Y, inv_ny, neg_mask, &acc[2]);
    }

    final_kernel<<<1, 1, 0, stream>>>(acc, n_neg, out);
}